// Round 1
// baseline (16117.747 us; speedup 1.0000x reference)
//
#include <hip/hip_runtime.h>

// Problem constants (fixed by setup_inputs)
#define E_EDGES   400000
#define M_NODES   50000
#define PER_B     400000   // M*d floats per batch
#define VEC_N     800000   // B*M*d floats
#define N4        200000   // VEC_N/4 (float4 elements)
#define N4_PER_B  100000   // per-batch float4 elements
#define CG_ITERS  20
#define EPSF      1e-12f

// scalar layout in ws: [0..1] rsold, [2..3] rsnew, [4..5] pAp, [6..7] alpha, [8..9] beta

__device__ __forceinline__ float waveReduce(float v) {
#pragma unroll
    for (int off = 32; off > 0; off >>= 1)
        v += __shfl_down(v, off, 64);
    return v;
}

__global__ void k_zero_scalars(float* __restrict__ s) {
    if (threadIdx.x < 16) s[threadIdx.x] = 0.0f;
}

// x = c0; Ap = c0  (Ap pre-init for matvec: A p = p + scatter(acc))
__global__ void k_init(const float4* __restrict__ c0, float4* __restrict__ x,
                       float4* __restrict__ Ap) {
    int i = blockIdx.x * blockDim.x + threadIdx.x;
    if (i < N4) { float4 v = c0[i]; x[i] = v; Ap[i] = v; }
}

// per-edge: r = Rs*p_s - Rd*p_d ; Ap[src] += Rs^T r ; Ap[dst] -= Rd^T r
__global__ void k_edge(const float* __restrict__ p, float* __restrict__ Ap,
                       const int* __restrict__ src, const int* __restrict__ dst,
                       const float* __restrict__ Rsg, const float* __restrict__ Rdg) {
    int e = blockIdx.x * blockDim.x + threadIdx.x;
    if (e >= E_EDGES) return;
    const int s = src[e];
    const int t = dst[e];
    float Rs[64], Rd[64];
    {
        const float4* a = (const float4*)(Rsg + (size_t)e * 64);
        const float4* b = (const float4*)(Rdg + (size_t)e * 64);
        float4* ra = (float4*)Rs;
        float4* rb = (float4*)Rd;
#pragma unroll
        for (int i = 0; i < 16; ++i) ra[i] = a[i];
#pragma unroll
        for (int i = 0; i < 16; ++i) rb[i] = b[i];
    }
#pragma unroll
    for (int b = 0; b < 2; ++b) {
        float ps[8], pd[8];
        {
            const float4* pp = (const float4*)(p + b * PER_B + s * 8);
            ((float4*)ps)[0] = pp[0];
            ((float4*)ps)[1] = pp[1];
            const float4* pq = (const float4*)(p + b * PER_B + t * 8);
            ((float4*)pd)[0] = pq[0];
            ((float4*)pd)[1] = pq[1];
        }
        float rr[8];
#pragma unroll
        for (int a = 0; a < 8; ++a) {
            float acc = 0.0f;
#pragma unroll
            for (int d = 0; d < 8; ++d)
                acc += Rs[a * 8 + d] * ps[d] - Rd[a * 8 + d] * pd[d];
            rr[a] = acc;
        }
        float* as_ = Ap + b * PER_B + s * 8;
        float* ad_ = Ap + b * PER_B + t * 8;
#pragma unroll
        for (int d = 0; d < 8; ++d) {
            float cs = 0.0f, cd = 0.0f;
#pragma unroll
            for (int a = 0; a < 8; ++a) {
                cs += Rs[a * 8 + d] * rr[a];
                cd += Rd[a * 8 + d] * rr[a];
            }
            atomicAdd(&as_[d], cs);
            atomicAdd(&ad_[d], -cd);
        }
    }
}

// r = c0 - A*c0 ; p = r ; Ap = r (pre-init for next matvec) ; rsold += r.r
__global__ void k_init_r(const float4* __restrict__ c0, float4* __restrict__ Ap,
                         float4* __restrict__ r, float4* __restrict__ p,
                         float* __restrict__ scal) {
    int i = blockIdx.x * blockDim.x + threadIdx.x;
    float s0 = 0.0f, s1 = 0.0f;
    if (i < N4) {
        float4 c = c0[i];
        float4 a = Ap[i];
        float4 rv = make_float4(c.x - a.x, c.y - a.y, c.z - a.z, c.w - a.w);
        r[i] = rv; p[i] = rv; Ap[i] = rv;
        float d = rv.x * rv.x + rv.y * rv.y + rv.z * rv.z + rv.w * rv.w;
        if (i < N4_PER_B) s0 = d; else s1 = d;
    }
    s0 = waveReduce(s0);
    s1 = waveReduce(s1);
    if ((threadIdx.x & 63) == 0) {
        if (s0 != 0.0f) atomicAdd(&scal[0], s0);
        if (s1 != 0.0f) atomicAdd(&scal[1], s1);
    }
}

// pAp += p . Ap   (per batch)
__global__ void k_dot(const float4* __restrict__ p, const float4* __restrict__ Ap,
                      float* __restrict__ scal) {
    int i = blockIdx.x * blockDim.x + threadIdx.x;
    float s0 = 0.0f, s1 = 0.0f;
    if (i < N4) {
        float4 a = p[i];
        float4 b = Ap[i];
        float d = a.x * b.x + a.y * b.y + a.z * b.z + a.w * b.w;
        if (i < N4_PER_B) s0 = d; else s1 = d;
    }
    s0 = waveReduce(s0);
    s1 = waveReduce(s1);
    if ((threadIdx.x & 63) == 0) {
        if (s0 != 0.0f) atomicAdd(&scal[4], s0);
        if (s1 != 0.0f) atomicAdd(&scal[5], s1);
    }
}

// alpha = rsold/(pAp+eps); rsnew = 0
__global__ void k_alpha(float* __restrict__ s) {
    int b = threadIdx.x;
    if (b < 2) {
        s[6 + b] = s[b] / (s[4 + b] + EPSF);
        s[2 + b] = 0.0f;
    }
}

// x += alpha p ; r -= alpha Ap ; rsnew += r.r
__global__ void k_update(float4* __restrict__ x, const float4* __restrict__ p,
                         const float4* __restrict__ Ap, float4* __restrict__ r,
                         float* __restrict__ scal) {
    int i = blockIdx.x * blockDim.x + threadIdx.x;
    float s0 = 0.0f, s1 = 0.0f;
    if (i < N4) {
        int b = (i < N4_PER_B) ? 0 : 1;
        float al = scal[6 + b];
        float4 xv = x[i], pv = p[i], av = Ap[i], rv = r[i];
        xv.x += al * pv.x; xv.y += al * pv.y; xv.z += al * pv.z; xv.w += al * pv.w;
        rv.x -= al * av.x; rv.y -= al * av.y; rv.z -= al * av.z; rv.w -= al * av.w;
        x[i] = xv; r[i] = rv;
        float d = rv.x * rv.x + rv.y * rv.y + rv.z * rv.z + rv.w * rv.w;
        if (b == 0) s0 = d; else s1 = d;
    }
    s0 = waveReduce(s0);
    s1 = waveReduce(s1);
    if ((threadIdx.x & 63) == 0) {
        if (s0 != 0.0f) atomicAdd(&scal[2], s0);
        if (s1 != 0.0f) atomicAdd(&scal[3], s1);
    }
}

// beta = rsnew/(rsold+eps); rsold = rsnew; pAp = 0
__global__ void k_beta(float* __restrict__ s) {
    int b = threadIdx.x;
    if (b < 2) {
        s[8 + b] = s[2 + b] / (s[b] + EPSF);
        s[b] = s[2 + b];
        s[4 + b] = 0.0f;
    }
}

// p = r + beta p ; Ap = p (pre-init for next matvec)
__global__ void k_pupdate(float4* __restrict__ p, const float4* __restrict__ r,
                          float4* __restrict__ Ap, const float* __restrict__ scal) {
    int i = blockIdx.x * blockDim.x + threadIdx.x;
    if (i < N4) {
        int b = (i < N4_PER_B) ? 0 : 1;
        float be = scal[8 + b];
        float4 rv = r[i], pv = p[i];
        float4 pn = make_float4(rv.x + be * pv.x, rv.y + be * pv.y,
                                rv.z + be * pv.z, rv.w + be * pv.w);
        p[i] = pn;
        Ap[i] = pn;
    }
}

extern "C" void kernel_launch(void* const* d_in, const int* in_sizes, int n_in,
                              void* d_out, int out_size, void* d_ws, size_t ws_size,
                              hipStream_t stream) {
    const float* c0 = (const float*)d_in[0];
    const int* src  = (const int*)d_in[1];
    const int* dst  = (const int*)d_in[2];
    const float* Rs = (const float*)d_in[3];
    const float* Rd = (const float*)d_in[4];

    float* x  = (float*)d_out;
    float* ws = (float*)d_ws;
    float* r    = ws;                 // 800000 floats
    float* p    = ws + VEC_N;         // 800000 floats
    float* Ap   = ws + 2 * VEC_N;     // 800000 floats
    float* scal = ws + 3 * VEC_N;     // 16 floats

    const int BLK = 256;
    const int grid_v = (N4 + BLK - 1) / BLK;
    const int grid_e = (E_EDGES + BLK - 1) / BLK;

    k_zero_scalars<<<1, 32, 0, stream>>>(scal);
    k_init<<<grid_v, BLK, 0, stream>>>((const float4*)c0, (float4*)x, (float4*)Ap);
    k_edge<<<grid_e, BLK, 0, stream>>>(c0, Ap, src, dst, Rs, Rd);
    k_init_r<<<grid_v, BLK, 0, stream>>>((const float4*)c0, (float4*)Ap,
                                         (float4*)r, (float4*)p, scal);

    for (int it = 0; it < CG_ITERS; ++it) {
        k_edge<<<grid_e, BLK, 0, stream>>>(p, Ap, src, dst, Rs, Rd);
        k_dot<<<grid_v, BLK, 0, stream>>>((const float4*)p, (const float4*)Ap, scal);
        k_alpha<<<1, 32, 0, stream>>>(scal);
        k_update<<<grid_v, BLK, 0, stream>>>((float4*)x, (const float4*)p,
                                             (const float4*)Ap, (float4*)r, scal);
        k_beta<<<1, 32, 0, stream>>>(scal);
        k_pupdate<<<grid_v, BLK, 0, stream>>>((float4*)p, (const float4*)r,
                                              (float4*)Ap, scal);
    }
}

// Round 2
// 5584.775 us; speedup vs baseline: 2.8860x; 2.8860x over previous
//
#include <hip/hip_runtime.h>
#include <hip/hip_fp16.h>

// Problem constants (fixed by setup_inputs)
#define E_EDGES   400000
#define M_NODES   50000
#define N_INC     800000   // 2*E incidences
#define PER_B     400000   // M*d floats per batch
#define VEC_N     800000   // B*M*d floats
#define N4        200000   // VEC_N/4
#define N4_PER_B  100000
#define CG_ITERS  20
#define EPSF      1e-12f

// scal layout: [0..1] rsold, [2..3] rsnew, [4..5] pAp, [6..7] alpha, [8..9] beta

__device__ __forceinline__ float waveReduce(float v) {
#pragma unroll
    for (int off = 32; off > 0; off >>= 1)
        v += __shfl_down(v, off, 64);
    return v;
}

__global__ void k_zero_scalars(float* __restrict__ s) {
    if (threadIdx.x < 16) s[threadIdx.x] = 0.0f;
}

__global__ void k_zero_cnt(int* __restrict__ cnt) {
    int i = blockIdx.x * blockDim.x + threadIdx.x;
    if (i < M_NODES) cnt[i] = 0;
}

__global__ void k_hist(const int* __restrict__ src, const int* __restrict__ dst,
                       int* __restrict__ cnt) {
    int e = blockIdx.x * blockDim.x + threadIdx.x;
    if (e < E_EDGES) {
        atomicAdd(&cnt[src[e]], 1);
        atomicAdd(&cnt[dst[e]], 1);
    }
}

// single-block exclusive scan of cnt[M_NODES] -> off[0..M], cursor copy
#define SCAN_T 1024
__global__ void k_scan(const int* __restrict__ cnt, int* __restrict__ off,
                       int* __restrict__ cursor) {
    __shared__ int part[SCAN_T];
    int t = threadIdx.x;
    const int chunk = (M_NODES + SCAN_T - 1) / SCAN_T;
    int beg = t * chunk;
    int end = beg + chunk; if (end > M_NODES) end = M_NODES;
    if (beg > M_NODES) beg = M_NODES;
    int s = 0;
    for (int i = beg; i < end; ++i) s += cnt[i];
    part[t] = s;
    __syncthreads();
    for (int st = 1; st < SCAN_T; st <<= 1) {
        int v = (t >= st) ? part[t - st] : 0;
        __syncthreads();
        part[t] += v;
        __syncthreads();
    }
    int run = (t == 0) ? 0 : part[t - 1];
    for (int i = beg; i < end; ++i) {
        off[i] = run; cursor[i] = run;
        run += cnt[i];
    }
    if (t == SCAN_T - 1) off[M_NODES] = run;
}

// scatter incidences: value = (e<<1) | side   (side 0 = out/src, 1 = in/dst)
__global__ void k_scatter(const int* __restrict__ src, const int* __restrict__ dst,
                          int* __restrict__ cursor, int* __restrict__ inc) {
    int e = blockIdx.x * blockDim.x + threadIdx.x;
    if (e < E_EDGES) {
        int p0 = atomicAdd(&cursor[src[e]], 1);
        inc[p0] = (e << 1);
        int p1 = atomicAdd(&cursor[dst[e]], 1);
        inc[p1] = (e << 1) | 1;
    }
}

// per incidence: W_i = X^T Y (fp16, row-major 8x8), nb_i = neighbor node
// side 0 (at src): X=Rs, Y=Rd, nb=dst ;  side 1 (at dst): X=Rd, Y=Rs, nb=src
__global__ void k_buildW(const int* __restrict__ inc, const int* __restrict__ src,
                         const int* __restrict__ dst,
                         const float* __restrict__ Rs, const float* __restrict__ Rd,
                         __half* __restrict__ W, int* __restrict__ nb) {
    int i = blockIdx.x * blockDim.x + threadIdx.x;
    if (i >= N_INC) return;
    int v = inc[i];
    int e = v >> 1, side = v & 1;
    const float* X = (side ? Rd : Rs) + (size_t)e * 64;
    const float* Y = (side ? Rs : Rd) + (size_t)e * 64;
    nb[i] = side ? src[e] : dst[e];
    float Yr[64];
    {
        const float4* yp = (const float4*)Y;
        float4* yr = (float4*)Yr;
#pragma unroll
        for (int k = 0; k < 16; ++k) yr[k] = yp[k];
    }
    __half* wo = W + ((size_t)i << 6);
#pragma unroll
    for (int a = 0; a < 8; ++a) {
        float xc[8];
#pragma unroll
        for (int c = 0; c < 8; ++c) xc[c] = X[c * 8 + a];
        float row[8];
#pragma unroll
        for (int j = 0; j < 8; ++j) row[j] = 0.0f;
#pragma unroll
        for (int c = 0; c < 8; ++c)
#pragma unroll
            for (int j = 0; j < 8; ++j) row[j] += xc[c] * Yr[c * 8 + j];
        union { float4 f; __half2 h[4]; } u;
#pragma unroll
        for (int k = 0; k < 4; ++k)
            u.h[k] = __floats2half2_rn(row[2 * k], row[2 * k + 1]);
        *(float4*)(wo + a * 8) = u.f;
    }
}

// per (node m, row a): diag[m][a][:] = I_row + sum over incidences of (R^T R) row a
__global__ void k_diag(const int* __restrict__ off, const int* __restrict__ inc,
                       const float* __restrict__ Rs, const float* __restrict__ Rd,
                       float* __restrict__ diag) {
    int gt = blockIdx.x * blockDim.x + threadIdx.x;
    int m = gt >> 3, a = gt & 7;
    if (m >= M_NODES) return;
    float Dg[8];
#pragma unroll
    for (int j = 0; j < 8; ++j) Dg[j] = 0.0f;
    int beg = off[m], end = off[m + 1];
    for (int i = beg; i < end; ++i) {
        int v = inc[i];
        int e = v >> 1, side = v & 1;
        const float* R = (side ? Rd : Rs) + (size_t)e * 64;
#pragma unroll
        for (int c = 0; c < 8; ++c) {
            float xa = R[c * 8 + a];
            float4 y0 = *(const float4*)(R + c * 8);
            float4 y1 = *(const float4*)(R + c * 8 + 4);
            Dg[0] += xa * y0.x; Dg[1] += xa * y0.y; Dg[2] += xa * y0.z; Dg[3] += xa * y0.w;
            Dg[4] += xa * y1.x; Dg[5] += xa * y1.y; Dg[6] += xa * y1.z; Dg[7] += xa * y1.w;
        }
    }
    float* dout = diag + ((size_t)m << 6) + a * 8;
#pragma unroll
    for (int j = 0; j < 8; ++j)
        dout[j] = Dg[j] + ((j == a) ? 1.0f : 0.0f);
}

// gather matvec: Ap_m = Diag_m p_m - sum_i W_i p_nb(i) ; also pAp dot into scal[4/5]
__global__ void k_matvec(const float* __restrict__ p, float* __restrict__ Ap,
                         const int* __restrict__ off, const int* __restrict__ nb,
                         const __half* __restrict__ W, const float* __restrict__ diag,
                         float* __restrict__ scal) {
    int gt = blockIdx.x * blockDim.x + threadIdx.x;
    int m = gt >> 3, a = gt & 7;
    float d0 = 0.0f, d1 = 0.0f;
    if (m < M_NODES) {
        const float* dgp = diag + ((size_t)m << 6) + a * 8;
        float4 dg0 = *(const float4*)dgp;
        float4 dg1 = *(const float4*)(dgp + 4);
        const float* pm0 = p + (m << 3);
        const float* pm1 = p + PER_B + (m << 3);
        float4 q00 = *(const float4*)pm0, q01 = *(const float4*)(pm0 + 4);
        float4 q10 = *(const float4*)pm1, q11 = *(const float4*)(pm1 + 4);
        float acc0 = dg0.x * q00.x + dg0.y * q00.y + dg0.z * q00.z + dg0.w * q00.w
                   + dg1.x * q01.x + dg1.y * q01.y + dg1.z * q01.z + dg1.w * q01.w;
        float acc1 = dg0.x * q10.x + dg0.y * q10.y + dg0.z * q10.z + dg0.w * q10.w
                   + dg1.x * q11.x + dg1.y * q11.y + dg1.z * q11.z + dg1.w * q11.w;
        int beg = off[m], end = off[m + 1];
        for (int i = beg; i < end; ++i) {
            int nbm = nb[i];
            union { float4 f; __half2 h[4]; } u;
            u.f = *(const float4*)(W + ((size_t)i << 6) + (a << 3));
            float2 w0 = __half22float2(u.h[0]);
            float2 w1 = __half22float2(u.h[1]);
            float2 w2 = __half22float2(u.h[2]);
            float2 w3 = __half22float2(u.h[3]);
            const float* pn0 = p + (nbm << 3);
            const float* pn1 = p + PER_B + (nbm << 3);
            float4 n00 = *(const float4*)pn0, n01 = *(const float4*)(pn0 + 4);
            float4 n10 = *(const float4*)pn1, n11 = *(const float4*)(pn1 + 4);
            acc0 -= w0.x * n00.x + w0.y * n00.y + w1.x * n00.z + w1.y * n00.w
                  + w2.x * n01.x + w2.y * n01.y + w3.x * n01.z + w3.y * n01.w;
            acc1 -= w0.x * n10.x + w0.y * n10.y + w1.x * n10.z + w1.y * n10.w
                  + w2.x * n11.x + w2.y * n11.y + w3.x * n11.z + w3.y * n11.w;
        }
        Ap[(m << 3) + a] = acc0;
        Ap[PER_B + (m << 3) + a] = acc1;
        float pa0 = p[(m << 3) + a];
        float pa1 = p[PER_B + (m << 3) + a];
        d0 = pa0 * acc0;
        d1 = pa1 * acc1;
    }
    d0 = waveReduce(d0);
    d1 = waveReduce(d1);
    if ((threadIdx.x & 63) == 0) {
        if (d0 != 0.0f) atomicAdd(&scal[4], d0);
        if (d1 != 0.0f) atomicAdd(&scal[5], d1);
    }
}

// x = c0
__global__ void k_init(const float4* __restrict__ c0, float4* __restrict__ x) {
    int i = blockIdx.x * blockDim.x + threadIdx.x;
    if (i < N4) x[i] = c0[i];
}

// r = c0 - Ap ; p = r ; rsold += r.r ; zero pAp slots
__global__ void k_init_r(const float4* __restrict__ c0, const float4* __restrict__ Ap,
                         float4* __restrict__ r, float4* __restrict__ p,
                         float* __restrict__ scal) {
    int i = blockIdx.x * blockDim.x + threadIdx.x;
    if (i == 0) { scal[4] = 0.0f; scal[5] = 0.0f; }
    float s0 = 0.0f, s1 = 0.0f;
    if (i < N4) {
        float4 c = c0[i];
        float4 a = Ap[i];
        float4 rv = make_float4(c.x - a.x, c.y - a.y, c.z - a.z, c.w - a.w);
        r[i] = rv; p[i] = rv;
        float d = rv.x * rv.x + rv.y * rv.y + rv.z * rv.z + rv.w * rv.w;
        if (i < N4_PER_B) s0 = d; else s1 = d;
    }
    s0 = waveReduce(s0);
    s1 = waveReduce(s1);
    if ((threadIdx.x & 63) == 0) {
        if (s0 != 0.0f) atomicAdd(&scal[0], s0);
        if (s1 != 0.0f) atomicAdd(&scal[1], s1);
    }
}

// alpha = rsold/(pAp+eps); rsnew = 0
__global__ void k_alpha(float* __restrict__ s) {
    int b = threadIdx.x;
    if (b < 2) {
        s[6 + b] = s[b] / (s[4 + b] + EPSF);
        s[2 + b] = 0.0f;
    }
}

// x += alpha p ; r -= alpha Ap ; rsnew += r.r
__global__ void k_update(float4* __restrict__ x, const float4* __restrict__ p,
                         const float4* __restrict__ Ap, float4* __restrict__ r,
                         float* __restrict__ scal) {
    int i = blockIdx.x * blockDim.x + threadIdx.x;
    float s0 = 0.0f, s1 = 0.0f;
    if (i < N4) {
        int b = (i < N4_PER_B) ? 0 : 1;
        float al = scal[6 + b];
        float4 xv = x[i], pv = p[i], av = Ap[i], rv = r[i];
        xv.x += al * pv.x; xv.y += al * pv.y; xv.z += al * pv.z; xv.w += al * pv.w;
        rv.x -= al * av.x; rv.y -= al * av.y; rv.z -= al * av.z; rv.w -= al * av.w;
        x[i] = xv; r[i] = rv;
        float d = rv.x * rv.x + rv.y * rv.y + rv.z * rv.z + rv.w * rv.w;
        if (b == 0) s0 = d; else s1 = d;
    }
    s0 = waveReduce(s0);
    s1 = waveReduce(s1);
    if ((threadIdx.x & 63) == 0) {
        if (s0 != 0.0f) atomicAdd(&scal[2], s0);
        if (s1 != 0.0f) atomicAdd(&scal[3], s1);
    }
}

// beta = rsnew/(rsold+eps); rsold = rsnew; pAp = 0
__global__ void k_beta(float* __restrict__ s) {
    int b = threadIdx.x;
    if (b < 2) {
        s[8 + b] = s[2 + b] / (s[b] + EPSF);
        s[b] = s[2 + b];
        s[4 + b] = 0.0f;
    }
}

// p = r + beta p
__global__ void k_pupdate(float4* __restrict__ p, const float4* __restrict__ r,
                          const float* __restrict__ scal) {
    int i = blockIdx.x * blockDim.x + threadIdx.x;
    if (i < N4) {
        int b = (i < N4_PER_B) ? 0 : 1;
        float be = scal[8 + b];
        float4 rv = r[i], pv = p[i];
        p[i] = make_float4(rv.x + be * pv.x, rv.y + be * pv.y,
                           rv.z + be * pv.z, rv.w + be * pv.w);
    }
}

extern "C" void kernel_launch(void* const* d_in, const int* in_sizes, int n_in,
                              void* d_out, int out_size, void* d_ws, size_t ws_size,
                              hipStream_t stream) {
    const float* c0 = (const float*)d_in[0];
    const int* src  = (const int*)d_in[1];
    const int* dst  = (const int*)d_in[2];
    const float* Rs = (const float*)d_in[3];
    const float* Rd = (const float*)d_in[4];

    float* x = (float*)d_out;
    char* w = (char*)d_ws;
    size_t o = 0;
    auto alloc = [&](size_t bytes) { char* c = w + o; o = (o + bytes + 255) & ~(size_t)255; return c; };
    float* r      = (float*)alloc(VEC_N * 4);
    float* p      = (float*)alloc(VEC_N * 4);
    float* Ap     = (float*)alloc(VEC_N * 4);
    float* scal   = (float*)alloc(64);
    int*   cnt    = (int*)alloc(M_NODES * 4);      // also cursor
    int*   offa   = (int*)alloc((M_NODES + 1) * 4);
    int*   cursor = (int*)alloc(M_NODES * 4);
    int*   inc    = (int*)alloc(N_INC * 4);
    int*   nb     = (int*)alloc(N_INC * 4);
    float* diag   = (float*)alloc((size_t)M_NODES * 64 * 4);
    __half* W     = (__half*)alloc((size_t)N_INC * 64 * 2);

    const int BLK = 256;
    const int grid_v  = (N4 + BLK - 1) / BLK;
    const int grid_e  = (E_EDGES + BLK - 1) / BLK;
    const int grid_m  = (M_NODES + BLK - 1) / BLK;
    const int grid_i  = (N_INC + BLK - 1) / BLK;
    const int grid_n8 = (M_NODES * 8 + BLK - 1) / BLK;

    // ---- precompute CSR + W + diag (rebuilt every call; no state carried) ----
    k_zero_scalars<<<1, 32, 0, stream>>>(scal);
    k_zero_cnt<<<grid_m, BLK, 0, stream>>>(cnt);
    k_hist<<<grid_e, BLK, 0, stream>>>(src, dst, cnt);
    k_scan<<<1, SCAN_T, 0, stream>>>(cnt, offa, cursor);
    k_scatter<<<grid_e, BLK, 0, stream>>>(src, dst, cursor, inc);
    k_buildW<<<grid_i, BLK, 0, stream>>>(inc, src, dst, Rs, Rd, W, nb);
    k_diag<<<grid_n8, BLK, 0, stream>>>(offa, inc, Rs, Rd, diag);

    // ---- CG ----
    k_init<<<grid_v, BLK, 0, stream>>>((const float4*)c0, (float4*)x);
    k_matvec<<<grid_n8, BLK, 0, stream>>>(c0, Ap, offa, nb, W, diag, scal);
    k_init_r<<<grid_v, BLK, 0, stream>>>((const float4*)c0, (const float4*)Ap,
                                         (float4*)r, (float4*)p, scal);

    for (int it = 0; it < CG_ITERS; ++it) {
        k_matvec<<<grid_n8, BLK, 0, stream>>>(p, Ap, offa, nb, W, diag, scal);
        k_alpha<<<1, 32, 0, stream>>>(scal);
        k_update<<<grid_v, BLK, 0, stream>>>((float4*)x, (const float4*)p,
                                             (const float4*)Ap, (float4*)r, scal);
        if (it < CG_ITERS - 1) {
            k_beta<<<1, 32, 0, stream>>>(scal);
            k_pupdate<<<grid_v, BLK, 0, stream>>>((float4*)p, (const float4*)r, scal);
        }
    }
}